// Round 17
// baseline (163.938 us; speedup 1.0000x reference)
//
#include <hip/hip_runtime.h>
#include <hip/hip_bf16.h>

typedef short short8 __attribute__((ext_vector_type(8)));
typedef float floatx4 __attribute__((ext_vector_type(4)));

#define NGROUP 512
#define RREG 256
#define D 512
#define ROWS 131072
#define FBAR_ELEMS (NGROUP * D)   // 262144

__device__ __forceinline__ unsigned short f2bf(float f) {
    unsigned int u = __float_as_uint(f);
    unsigned int r = (u + 0x7fffu + ((u >> 16) & 1u)) >> 16;
    return (unsigned short)r;
}
__device__ __forceinline__ float fast_tanh(float x) {
    float cx = fminf(fmaxf(x, -9.5f), 9.5f);
    float e  = __builtin_amdgcn_exp2f(cx * 2.8853900817779268f);  // e^{2cx}
    return (e - 1.f) * __builtin_amdgcn_rcpf(e + 1.f);
}

// ---- kernel 1: W1 fp32 -> bf16, K-CHUNKED PRE-SWIZZLED layout (R16 verbatim) ----
// W1c = 16 chunks of 32 KiB. Chunk kc holds k in [kc*32,kc*32+32) for all 512
// cols: element (col, kc*32+kl) at chunk byte col*64 + ((kl*2) ^ (((col>>1)&3)<<4)).
__global__ __launch_bounds__(256) void conv_w1(const float* __restrict__ W1,
                                               unsigned short* __restrict__ W1c) {
    int tid = blockIdx.x * 256 + threadIdx.x;   // 0..65535
    int P = tid * 8;                            // byte offset in 512 KiB image
    int kc = P >> 15;
    int L = P & 32767;
    int col = L >> 6;
    int q = L & 63;
    int kl = (q ^ (((col >> 1) & 3) << 4)) >> 1;   // multiple of 4
    const float* src = W1 + col * 512 + kc * 32 + kl;
    float4 v = *reinterpret_cast<const float4*>(src);
    ushort4 o;
    o.x = f2bf(v.x); o.y = f2bf(v.y); o.z = f2bf(v.z); o.w = f2bf(v.w);
    *reinterpret_cast<ushort4*>((char*)W1c + P) = o;
}

// ---- kernel 2: score GEMM at 8 waves/SIMD ----
// 2048 blocks x 1024 threads (16 waves). Block = 64 rows x full N=512.
// Wave = 64 rows x 32 cols: acc[4][2] = 32 AGPR. Unified-file law from
// R1-R16: waves/SIMD = floor(512 / (2*ceil32(max(arch, acc)))) -> 8/SIMD
// needs arch<=32 AND acc<=32. launch_bounds(1024,8) caps arch at 32.
// LDS 76 KB -> 2 blocks/CU -> 32 waves/CU: latency hiding by TLP (R16
// post-mortem: at 4 waves/SIMD no pipe >40% busy; pure latency exposure).
// A: dbuf 2x4KB, thread packs 2 floats/step (4B ds_write); B: dbuf 2x32KB,
// wave-private 2KB DMA slices from pre-swizzled W1c; one barrier/step.
__global__ __launch_bounds__(1024, 8) void score_gemm(
    const float* __restrict__ x, const unsigned short* __restrict__ W1c,
    const float* __restrict__ b1, const float* __restrict__ W2v,
    float* __restrict__ inv_norm, float* __restrict__ scores) {

    __shared__ unsigned short A_lds[2][64 * 32];    // 2 x 4 KB
    __shared__ unsigned short B_lds[2][512 * 32];   // 2 x 32 KB
    __shared__ float inv_s[64];

    const int t = threadIdx.x;
    const int lane = t & 63;
    const int w = t >> 6;          // wave 0..15 -> cols w*32..w*32+32
    const int cl = lane & 15;
    const int hi = lane >> 4;
    const size_t row0 = (size_t)blockIdx.x * 64;

    // wave-private B stage: 32-col slice of chunk kc (2 KB, 2 DMA instrs)
    auto stageB = [&](int buf, int kc) {
        const char* gb = (const char*)W1c + kc * 32768 + w * 2048 + lane * 16;
        char* lb = (char*)B_lds[buf] + w * 2048;
        #pragma unroll
        for (int i = 0; i < 2; ++i) {
            __builtin_amdgcn_global_load_lds(
                (const __attribute__((address_space(1))) void*)(gb + i * 1024),
                (__attribute__((address_space(3))) void*)(lb + i * 1024),
                16, 0, 0);
        }
    };

    // A staging: thread owns row t>>4, k-pair t&15 (2 floats -> 1 u32 bf16x2)
    const int arow = t >> 4;
    const int kq = t & 15;
    const int abyte = arow * 64 + ((kq * 4) ^ (((arow >> 1) & 3) << 4));
    const float* xp = x + (row0 + arow) * (size_t)D + kq * 2;

    float ssacc = 0.f;
    auto packA = [&](int buf, float2 v) {
        ssacc += v.x * v.x + v.y * v.y;
        unsigned int pk = (unsigned int)f2bf(v.x) | ((unsigned int)f2bf(v.y) << 16);
        *reinterpret_cast<unsigned int*>((char*)A_lds[buf] + abyte) = pk;
    };

    // ---- prologue: chunk 0 ----
    stageB(0, 0);
    packA(0, *reinterpret_cast<const float2*>(xp));
    __syncthreads();   // A(0) visible; B(0) DMA drained

    floatx4 acc[4][2];
    #pragma unroll
    for (int tt = 0; tt < 4; ++tt) {
        acc[tt][0] = floatx4{0, 0, 0, 0};
        acc[tt][1] = floatx4{0, 0, 0, 0};
    }

    // shared A/B fragment swizzle: both row=tt*16+cl and col=w*32+f*16+cl
    // reduce to key ((cl>>1)&3) (tile/wave offsets vanish mod 4)
    const int fofs = (hi * 16) ^ (((cl >> 1) & 3) << 4);

    // ---- K loop: 16 steps of 32 k ----
    #pragma unroll 2
    for (int s = 0; s < 16; ++s) {
        const int cur = s & 1, nx = cur ^ 1;

        float2 xv;
        if (s < 15) {
            xv = *reinterpret_cast<const float2*>(xp + (s + 1) * 32);  // next A
            stageB(nx, s + 1);                                         // next B
        }

        short8 bfr0 = *reinterpret_cast<const short8*>(
            (char*)B_lds[cur] + (w * 32 + cl) * 64 + fofs);
        short8 bfr1 = *reinterpret_cast<const short8*>(
            (char*)B_lds[cur] + (w * 32 + 16 + cl) * 64 + fofs);
        #pragma unroll
        for (int tt = 0; tt < 4; ++tt) {
            short8 afr = *reinterpret_cast<const short8*>(
                (char*)A_lds[cur] + (tt * 16 + cl) * 64 + fofs);
            acc[tt][0] = __builtin_amdgcn_mfma_f32_16x16x32_bf16(afr, bfr0, acc[tt][0], 0, 0, 0);
            acc[tt][1] = __builtin_amdgcn_mfma_f32_16x16x32_bf16(afr, bfr1, acc[tt][1], 0, 0, 0);
        }

        if (s < 15) {
            packA(nx, xv);
            __syncthreads();   // A(s+1)/B(s+1) ready; all waves done with [cur]
        }
    }

    // ---- inv: reduce ssacc over the 16 consecutive lanes sharing a row ----
    ssacc += __shfl_xor(ssacc, 1, 16);
    ssacc += __shfl_xor(ssacc, 2, 16);
    ssacc += __shfl_xor(ssacc, 4, 16);
    ssacc += __shfl_xor(ssacc, 8, 16);
    if (kq == 0) {
        float inv = 1.0f / fmaxf(sqrtf(ssacc), 1e-12f);
        inv_s[arow] = inv;
        inv_norm[row0 + arow] = inv;
    }
    __syncthreads();   // inv_s visible; all A/B LDS reads done

    float* scorebuf = (float*)A_lds;   // [16][64] alias (A dead)

    // ---- epilogue per row-tile (low reg pressure under the 32-cap) ----
    #pragma unroll
    for (int tt = 0; tt < 4; ++tt) {
        floatx4 iv = *reinterpret_cast<const floatx4*>(&inv_s[tt * 16 + hi * 4]);
        float sp[4] = {0.f, 0.f, 0.f, 0.f};
        #pragma unroll
        for (int f = 0; f < 2; ++f) {
            int col = w * 32 + f * 16 + cl;
            float wv = W2v[col];
            float bb = b1[col];
            #pragma unroll
            for (int i = 0; i < 4; ++i)
                sp[i] += wv * fast_tanh(acc[tt][f][i] * iv[i] + bb);
        }
        #pragma unroll
        for (int i = 0; i < 4; ++i) {
            float v = sp[i];
            v += __shfl_xor(v, 1, 64);
            v += __shfl_xor(v, 2, 64);
            v += __shfl_xor(v, 4, 64);
            v += __shfl_xor(v, 8, 64);
            if (cl == 0) scorebuf[w * 64 + tt * 16 + hi * 4 + i] = v;
        }
    }
    __syncthreads();

    // sum the 16 per-wave col-slice partials -> final scores
    if (t < 64) {
        float s = 0.f;
        #pragma unroll
        for (int q = 0; q < 16; ++q) s += scorebuf[q * 64 + t];
        scores[row0 + t] = s;
    }
}

// ---- kernel 3: softmax over r + fp32 weighted pooling (R16 verbatim) ----
__global__ __launch_bounds__(512) void softmax_pool(
    const float* __restrict__ x, const float* __restrict__ inv_norm,
    const float* __restrict__ scores, float* __restrict__ out) {

    __shared__ float F[RREG];
    __shared__ float wts[RREG];
    const int t = threadIdx.x;
    const int g = blockIdx.x;

    float s = 0.f, e = 0.f;
    if (t < RREG) { s = scores[g * RREG + t]; F[t] = s; }
    __syncthreads();
    for (int off = 128; off > 0; off >>= 1) {
        if (t < off) F[t] = fmaxf(F[t], F[t + off]);
        __syncthreads();
    }
    float mx = F[0];
    __syncthreads();
    if (t < RREG) { e = expf(s - mx); F[t] = e; }
    __syncthreads();
    for (int off = 128; off > 0; off >>= 1) {
        if (t < off) F[t] += F[t + off];
        __syncthreads();
    }
    float denom = F[0];
    if (t < RREG) {
        float al = e / denom;
        out[FBAR_ELEMS + (size_t)g * RREG + t] = al;          // output 1: alphas
        wts[t] = al * inv_norm[(size_t)g * RREG + t];
    }
    __syncthreads();

    // fbar[d=t] = sum_r (alpha_r * inv_r) * x[g,r,t]  (coalesced 2 KB/row)
    float a = 0.f;
    const float* xb = x + (size_t)g * RREG * D + t;
    #pragma unroll 16
    for (int r = 0; r < RREG; ++r) a += wts[r] * xb[(size_t)r * D];
    out[(size_t)g * D + t] = a;                               // output 0: fbar
}

extern "C" void kernel_launch(void* const* d_in, const int* in_sizes, int n_in,
                              void* d_out, int out_size, void* d_ws, size_t ws_size,
                              hipStream_t stream) {
    const float* x  = (const float*)d_in[0];
    const float* W1 = (const float*)d_in[1];
    const float* b1 = (const float*)d_in[2];
    const float* w2 = (const float*)d_in[3];
    // b2 (d_in[4]) shifts all scores uniformly -> softmax-invariant -> unused.
    float* out = (float*)d_out;

    unsigned short* W1c = (unsigned short*)d_ws;                     // 512 KiB
    float* inv_norm = (float*)((char*)d_ws + 524288);                // 512 KiB
    float* scores   = (float*)((char*)d_ws + 1048576);               // 512 KiB

    conv_w1<<<256, 256, 0, stream>>>(W1, W1c);
    score_gemm<<<ROWS / 64, 1024, 0, stream>>>(x, W1c, b1, w2, inv_norm, scores);
    softmax_pool<<<NGROUP, 512, 0, stream>>>(x, inv_norm, scores, out);
}